// Round 1
// baseline (330.565 us; speedup 1.0000x reference)
//
#include <hip/hip_runtime.h>

// Problem constants
#define BH      65536     // B*H = 512*128
#define NSEC    32        // N sectors
#define DSTATE  75        // D
#define NAUG    17
#define SMDIM   32
#define HALFD   128
#define EMBD    256
#define NROWS   8         // rows per block
#define NTHREADS 256

__global__ __launch_bounds__(256) void att_state_enc_kernel(
    const float* __restrict__ state,
    const float* __restrict__ token_W, const float* __restrict__ token_b,
    const float* __restrict__ query_W, const float* __restrict__ query_b,
    const float* __restrict__ rbs_p, const float* __restrict__ vb_p, const float* __restrict__ ivb_p,
    const float* __restrict__ att_ln_w, const float* __restrict__ att_ln_b,
    const float* __restrict__ non_W, const float* __restrict__ non_b,
    const float* __restrict__ spfb_W, const float* __restrict__ spfb_b,
    const float* __restrict__ sp_gate_p,
    const float* __restrict__ spatial_W, const float* __restrict__ spatial_b,
    const float* __restrict__ fuse_W, const float* __restrict__ fuse_b,
    const float* __restrict__ ln_w, const float* __restrict__ ln_b,
    float* __restrict__ out_x, float* __restrict__ out_tf)
{
    __shared__ float s_state[NROWS][DSTATE];
    __shared__ float s_tok[NROWS * 32 * 33];      // [(g*32+n)*33 + k], padded
    __shared__ float s_na[NROWS][NAUG];
    __shared__ float s_q[NROWS][32];
    __shared__ float s_w[NROWS][32];
    __shared__ float s_ctx[NROWS][32];
    __shared__ __align__(16) float s_x[NROWS][256];
    __shared__ float s_y[NROWS][257];
    __shared__ float s_mr[NROWS][2];
    __shared__ float s_tf[NROWS][2];

    const int t = threadIdx.x;
    const long rowbase = (long)blockIdx.x * NROWS;

    // ---- load 8 rows of state (contiguous 600 floats) ----
    for (int i = t; i < NROWS * DSTATE; i += NTHREADS) {
        ((float*)s_state)[i] = state[rowbase * DSTATE + i];
    }
    __syncthreads();

    const int g = t >> 5;         // group (row) 0..7
    const int l = t & 31;         // lane within group

    const float rbs = rbs_p[0];
    const float vb  = vb_p[0];
    const float ivb = ivb_p[0];

    // ---- per-row stats (32 lanes per row, shuffle-width-32 reductions) ----
    {
        float sec = s_state[g][l];
        float dif = s_state[g][32 + l];
        float vld = (sec < 0.95f) ? 1.0f : 0.0f;
        float da  = fabsf(dif);
        float mn = sec, sm = sec, vs = vld, ds = da, dmx = da;
        for (int m = 16; m >= 1; m >>= 1) {
            mn  = fminf(mn, __shfl_xor(mn, m, 32));
            sm += __shfl_xor(sm, m, 32);
            vs += __shfl_xor(vs, m, 32);
            ds += __shfl_xor(ds, m, 32);
            dmx = fmaxf(dmx, __shfl_xor(dmx, m, 32));
        }
        float min_r = mn;
        float mean_r = sm * (1.0f / 32.0f);
        float vr = vs * (1.0f / 32.0f);
        float dam = ds * (1.0f / 32.0f);
        float dax = dmx;
        float dyaw = fminf(fabsf(s_state[g][72]), 1.0f);

        if (l < 11)  s_na[g][l] = s_state[g][64 + l];
        if (l == 11) s_na[g][11] = min_r;
        if (l == 12) s_na[g][12] = mean_r;
        if (l == 13) s_na[g][13] = vr;
        if (l == 14) s_na[g][14] = dam;
        if (l == 15) s_na[g][15] = dax;
        if (l == 16) s_na[g][16] = dyaw;
        if (l == 0) { s_tf[g][0] = fminf(dam, 1.0f); s_tf[g][1] = dyaw; }
    }
    __syncthreads();

    // ---- q (relu(query @ non_aug)) : thread (g,l) does feature l ----
    {
        float acc = query_b[l];
        for (int j = 0; j < NAUG; ++j) acc += query_W[l * NAUG + j] * s_na[g][j];
        s_q[g][l] = fmaxf(acc, 0.0f);
    }
    // ---- tok_emb : thread (g, n=l) computes all 32 features ----
    {
        float sec = s_state[g][l];
        float dif = s_state[g][32 + l];
        float vld = (sec < 0.95f) ? 1.0f : 0.0f;
        float* dst = &s_tok[(g * 32 + l) * 33];
        for (int k = 0; k < 32; ++k) {
            float v = token_b[k] + token_W[k * 3 + 0] * sec
                                 + token_W[k * 3 + 1] * dif
                                 + token_W[k * 3 + 2] * vld;
            dst[k] = fmaxf(v, 0.0f);
        }
    }
    __syncthreads();

    // ---- score + softmax over sectors : thread (g, n=l) ----
    {
        float sec = s_state[g][l];
        float vld = (sec < 0.95f) ? 1.0f : 0.0f;
        const float* tk = &s_tok[(g * 32 + l) * 33];
        float acc = 0.0f;
        for (int k = 0; k < 32; ++k) acc += tk[k] * s_q[g][k];
        float score = acc * 0.17677669529663687f   // 1/sqrt(32)
                    + rbs * (1.0f - sec) + vb * vld + ivb * (1.0f - vld);
        float mx = score;
        for (int m = 16; m >= 1; m >>= 1) mx = fmaxf(mx, __shfl_xor(mx, m, 32));
        float e = expf(score - mx);
        float se = e;
        for (int m = 16; m >= 1; m >>= 1) se += __shfl_xor(se, m, 32);
        s_w[g][l] = e / se;
    }
    __syncthreads();

    // ---- ctx + LN32 : thread (g, k=l) ----
    {
        float acc = 0.0f;
        for (int n = 0; n < 32; ++n) acc += s_w[g][n] * s_tok[(g * 32 + n) * 33 + l];
        float sm = acc;
        for (int m = 16; m >= 1; m >>= 1) sm += __shfl_xor(sm, m, 32);
        float mean = sm * (1.0f / 32.0f);
        float d = acc - mean;
        float sq = d * d;
        for (int m = 16; m >= 1; m >>= 1) sq += __shfl_xor(sq, m, 32);
        float rstd = rsqrtf(sq * (1.0f / 32.0f) + 1e-5f);
        s_ctx[g][l] = d * rstd * att_ln_w[l] + att_ln_b[l];
    }
    __syncthreads();

    // ---- non_emb (threads 0..127) / sp_emb (threads 128..255), all 8 rows ----
    if (t < 128) {
        float wreg[NAUG];
        for (int j = 0; j < NAUG; ++j) wreg[j] = non_W[t * NAUG + j];
        float b = non_b[t];
        for (int gg = 0; gg < NROWS; ++gg) {
            float acc = b;
            for (int j = 0; j < NAUG; ++j) acc += wreg[j] * s_na[gg][j];
            s_x[gg][t] = fmaxf(acc, 0.0f);
        }
    } else {
        int o = t - 128;
        float w0 = spfb_W[o * 3 + 0], w1 = spfb_W[o * 3 + 1], w2 = spfb_W[o * 3 + 2];
        float bfb = spfb_b[o];
        float wreg[32];
        for (int k = 0; k < 32; ++k) wreg[k] = spatial_W[o * 32 + k];
        float bsp = spatial_b[o];
        float gate = sp_gate_p[0];
        float alpha = 1.0f / (1.0f + expf(-gate));
        for (int gg = 0; gg < NROWS; ++gg) {
            float fb = bfb + w0 * s_na[gg][11] + w1 * s_na[gg][12] + w2 * s_na[gg][13];
            fb = fmaxf(fb, 0.0f);
            float at = bsp;
            for (int k = 0; k < 32; ++k) at += wreg[k] * s_ctx[gg][k];
            at = fmaxf(at, 0.0f);
            s_x[gg][t] = alpha * at + (1.0f - alpha) * fb;
        }
    }
    __syncthreads();

    // ---- fuse (256x256 matvec, 8 rows): thread t = output feature ----
    {
        float acc[NROWS];
#pragma unroll
        for (int gg = 0; gg < NROWS; ++gg) acc[gg] = 0.0f;
        const float4* wrow4 = reinterpret_cast<const float4*>(fuse_W + (size_t)t * 256);
#pragma unroll 4
        for (int i4 = 0; i4 < 64; ++i4) {
            float4 w4 = wrow4[i4];
#pragma unroll
            for (int gg = 0; gg < NROWS; ++gg) {
                const float4 x4 = *reinterpret_cast<const float4*>(&s_x[gg][i4 * 4]);
                acc[gg] += w4.x * x4.x + w4.y * x4.y + w4.z * x4.z + w4.w * x4.w;
            }
        }
        float b = fuse_b[t];
        for (int gg = 0; gg < NROWS; ++gg) s_y[gg][t] = fmaxf(acc[gg] + b, 0.0f);
    }
    __syncthreads();

    // ---- LN256: group g reduces its row ----
    {
        float v[8];
        float sm = 0.0f;
#pragma unroll
        for (int m = 0; m < 8; ++m) { v[m] = s_y[g][l + 32 * m]; sm += v[m]; }
        for (int m = 16; m >= 1; m >>= 1) sm += __shfl_xor(sm, m, 32);
        float mean = sm * (1.0f / 256.0f);
        float sq = 0.0f;
#pragma unroll
        for (int m = 0; m < 8; ++m) { float d = v[m] - mean; sq += d * d; }
        for (int m = 16; m >= 1; m >>= 1) sq += __shfl_xor(sq, m, 32);
        float rstd = rsqrtf(sq * (1.0f / 256.0f) + 1e-5f);
        if (l == 0) { s_mr[g][0] = mean; s_mr[g][1] = rstd; }
    }
    __syncthreads();

    // ---- write outputs ----
    {
        float lw = ln_w[t], lb = ln_b[t];
        for (int gg = 0; gg < NROWS; ++gg) {
            float mean = s_mr[gg][0], rstd = s_mr[gg][1];
            float v = s_y[gg][t];
            out_x[(rowbase + gg) * 256 + t] = (v - mean) * rstd * lw + lb;
        }
        if (t < NROWS * 2) {
            int gg = t >> 1;
            out_tf[(rowbase + gg) * 2 + (t & 1)] = s_tf[gg][t & 1];
        }
    }
}

extern "C" void kernel_launch(void* const* d_in, const int* in_sizes, int n_in,
                              void* d_out, int out_size, void* d_ws, size_t ws_size,
                              hipStream_t stream) {
    const float* state     = (const float*)d_in[0];
    const float* token_W   = (const float*)d_in[1];
    const float* token_b   = (const float*)d_in[2];
    const float* query_W   = (const float*)d_in[3];
    const float* query_b   = (const float*)d_in[4];
    const float* rbs       = (const float*)d_in[5];
    const float* vbias     = (const float*)d_in[6];
    const float* ivbias    = (const float*)d_in[7];
    const float* att_ln_w  = (const float*)d_in[8];
    const float* att_ln_b  = (const float*)d_in[9];
    const float* non_W     = (const float*)d_in[10];
    const float* non_b     = (const float*)d_in[11];
    const float* spfb_W    = (const float*)d_in[12];
    const float* spfb_b    = (const float*)d_in[13];
    const float* sp_gate   = (const float*)d_in[14];
    const float* spatial_W = (const float*)d_in[15];
    const float* spatial_b = (const float*)d_in[16];
    const float* fuse_W    = (const float*)d_in[17];
    const float* fuse_b    = (const float*)d_in[18];
    const float* ln_w      = (const float*)d_in[19];
    const float* ln_b      = (const float*)d_in[20];

    float* out_x  = (float*)d_out;
    float* out_tf = out_x + (size_t)BH * EMBD;   // time_feats after x

    dim3 grid(BH / NROWS);
    dim3 block(NTHREADS);
    hipLaunchKernelGGL(att_state_enc_kernel, grid, block, 0, stream,
        state, token_W, token_b, query_W, query_b, rbs, vbias, ivbias,
        att_ln_w, att_ln_b, non_W, non_b, spfb_W, spfb_b, sp_gate,
        spatial_W, spatial_b, fuse_W, fuse_b, ln_w, ln_b,
        out_x, out_tf);
}

// Round 2
// 231.995 us; speedup vs baseline: 1.4249x; 1.4249x over previous
//
#include <hip/hip_runtime.h>

// Problem constants
#define BH      65536     // B*H = 512*128
#define DSTATE  75
#define NAUG    17
#define EMBD    256
#define NROWS   16        // rows per block
#define NTHREADS 256
#define NBLOCKS (BH / NROWS)   // 4096

typedef short bf16x8 __attribute__((ext_vector_type(8)));
typedef float f32x4  __attribute__((ext_vector_type(4)));

__device__ __forceinline__ unsigned short f32_to_bf16(float f) {
    union { float f; unsigned int u; } v; v.f = f;
    unsigned int u = v.u;
    u = u + 0x7FFFu + ((u >> 16) & 1u);   // round-to-nearest-even
    return (unsigned short)(u >> 16);
}

// ---- prep kernel: fuse_W (f32 [256 out][256 in]) -> bf16 fragment-swizzled ----
// Fragment element for (ks, ct, lane wl, j):  B[k][n] with n = ct*16 + (wl&15),
// k = ks*32 + (wl>>4)*8 + j, and B[k][n] = fuse_W[n][k].
// Output flat index: (((ks*16 + ct)*64) + wl)*8 + j   (so a wave reads 1KB contiguous)
__global__ __launch_bounds__(256) void prep_w_kernel(const float* __restrict__ fuse_W,
                                                     unsigned short* __restrict__ Wb) {
    int i = blockIdx.x * 256 + threadIdx.x;     // 8192 threads, 8 bf16 each
    int wl = i & 63;
    int ct = (i >> 6) & 15;
    int ks = i >> 10;
    int n = ct * 16 + (wl & 15);
    int k0 = ks * 32 + (wl >> 4) * 8;
    const float* src = fuse_W + n * 256 + k0;    // 8 consecutive f32, 32B aligned
    float4 a = *reinterpret_cast<const float4*>(src);
    float4 b = *reinterpret_cast<const float4*>(src + 4);
    unsigned int p0 = (unsigned int)f32_to_bf16(a.x) | ((unsigned int)f32_to_bf16(a.y) << 16);
    unsigned int p1 = (unsigned int)f32_to_bf16(a.z) | ((unsigned int)f32_to_bf16(a.w) << 16);
    unsigned int p2 = (unsigned int)f32_to_bf16(b.x) | ((unsigned int)f32_to_bf16(b.y) << 16);
    unsigned int p3 = (unsigned int)f32_to_bf16(b.z) | ((unsigned int)f32_to_bf16(b.w) << 16);
    uint4 out = make_uint4(p0, p1, p2, p3);
    reinterpret_cast<uint4*>(Wb)[i] = out;
}

__global__ __launch_bounds__(256) void att_state_enc_kernel(
    const float* __restrict__ state,
    const float* __restrict__ token_W, const float* __restrict__ token_b,
    const float* __restrict__ query_W, const float* __restrict__ query_b,
    const float* __restrict__ rbs_p, const float* __restrict__ vb_p, const float* __restrict__ ivb_p,
    const float* __restrict__ att_ln_w, const float* __restrict__ att_ln_b,
    const float* __restrict__ non_W, const float* __restrict__ non_b,
    const float* __restrict__ spfb_W, const float* __restrict__ spfb_b,
    const float* __restrict__ sp_gate_p,
    const float* __restrict__ spatial_W, const float* __restrict__ spatial_b,
    const unsigned short* __restrict__ Wb, const float* __restrict__ fuse_b,
    const float* __restrict__ ln_w, const float* __restrict__ ln_b,
    float* __restrict__ out_x, float* __restrict__ out_tf)
{
    __shared__ float  s_state[NROWS][DSTATE];
    __shared__ float4 s_tw4[32];                 // (token_b, tW0, tW1, tW2) per feature
    __shared__ float  s_na[NROWS][20];           // non_aug (17, padded to 20)
    __shared__ float  s_q[NROWS][32];
    __shared__ float  s_w[NROWS][32];
    __shared__ float  s_ctx[NROWS][32];
    __shared__ unsigned short s_x[NROWS][264];   // bf16 x, padded stride
    __shared__ float  s_y[NROWS][260];           // fuse output (pre-LN), padded
    __shared__ float  s_mr[NROWS][2];
    __shared__ float  s_tf2[NROWS][2];

    const int t = threadIdx.x;
    const int g = t >> 5;         // 32-lane group 0..7
    const int l = t & 31;
    const long rowbase = (long)blockIdx.x * NROWS;

    // ---- phase 1: load state rows + token weight pack ----
    for (int i = t; i < NROWS * DSTATE; i += NTHREADS)
        ((float*)s_state)[i] = state[rowbase * DSTATE + i];
    if (t < 32)
        s_tw4[t] = make_float4(token_b[t], token_W[3*t], token_W[3*t+1], token_W[3*t+2]);
    __syncthreads();

    const float rbs = rbs_p[0];
    const float vb  = vb_p[0];
    const float ivb = ivb_p[0];

    // ---- phase 2: per-row stats (rows g and g+8) ----
    for (int rr = 0; rr < 2; ++rr) {
        const int row = g + 8 * rr;
        float sec = s_state[row][l];
        float dif = s_state[row][32 + l];
        float vld = (sec < 0.95f) ? 1.0f : 0.0f;
        float da  = fabsf(dif);
        float mn = sec, sm = sec, vs = vld, ds = da, dmx = da;
        for (int m = 16; m >= 1; m >>= 1) {
            mn  = fminf(mn, __shfl_xor(mn, m, 32));
            sm += __shfl_xor(sm, m, 32);
            vs += __shfl_xor(vs, m, 32);
            ds += __shfl_xor(ds, m, 32);
            dmx = fmaxf(dmx, __shfl_xor(dmx, m, 32));
        }
        float min_r = mn, mean_r = sm * (1.0f/32.0f), vr = vs * (1.0f/32.0f);
        float dam = ds * (1.0f/32.0f), dax = dmx;
        float dyaw = fminf(fabsf(s_state[row][72]), 1.0f);
        if (l < 11)       s_na[row][l]  = s_state[row][64 + l];
        else if (l == 11) s_na[row][11] = min_r;
        else if (l == 12) s_na[row][12] = mean_r;
        else if (l == 13) s_na[row][13] = vr;
        else if (l == 14) s_na[row][14] = dam;
        else if (l == 15) s_na[row][15] = dax;
        else if (l == 16) s_na[row][16] = dyaw;
        if (l == 0) { s_tf2[row][0] = fminf(dam, 1.0f); s_tf2[row][1] = dyaw; }
    }
    __syncthreads();

    // ---- phase 3: q = relu(query @ non_aug) ----
    for (int rr = 0; rr < 2; ++rr) {
        const int row = g + 8 * rr;
        float acc = query_b[l];
        #pragma unroll
        for (int j = 0; j < NAUG; ++j) acc += query_W[l * NAUG + j] * s_na[row][j];
        s_q[row][l] = fmaxf(acc, 0.0f);
    }
    __syncthreads();

    // ---- phase 4: score + softmax (tok_emb recomputed on the fly) ----
    for (int rr = 0; rr < 2; ++rr) {
        const int row = g + 8 * rr;
        float sec = s_state[row][l];
        float dif = s_state[row][32 + l];
        float vld = (sec < 0.95f) ? 1.0f : 0.0f;
        float acc = 0.0f;
        for (int k = 0; k < 32; ++k) {
            float4 tw = s_tw4[k];
            float tok = fmaxf(tw.x + tw.y * sec + tw.z * dif + tw.w * vld, 0.0f);
            acc += tok * s_q[row][k];
        }
        float score = acc * 0.17677669529663687f
                    + rbs * (1.0f - sec) + vb * vld + ivb * (1.0f - vld);
        float mx = score;
        for (int m = 16; m >= 1; m >>= 1) mx = fmaxf(mx, __shfl_xor(mx, m, 32));
        float e = __expf(score - mx);
        float se = e;
        for (int m = 16; m >= 1; m >>= 1) se += __shfl_xor(se, m, 32);
        s_w[row][l] = e / se;
    }
    __syncthreads();

    // ---- phase 5: ctx + LN32 (thread l = feature k) ----
    for (int rr = 0; rr < 2; ++rr) {
        const int row = g + 8 * rr;
        const float4 tw = s_tw4[l];
        float acc = 0.0f;
        for (int n = 0; n < 32; ++n) {
            float w   = s_w[row][n];
            float sec = s_state[row][n];
            float dif = s_state[row][32 + n];
            float vld = (sec < 0.95f) ? 1.0f : 0.0f;
            float tok = fmaxf(tw.x + tw.y * sec + tw.z * dif + tw.w * vld, 0.0f);
            acc += w * tok;
        }
        float sm = acc;
        for (int m = 16; m >= 1; m >>= 1) sm += __shfl_xor(sm, m, 32);
        float mean = sm * (1.0f/32.0f);
        float d = acc - mean;
        float sq = d * d;
        for (int m = 16; m >= 1; m >>= 1) sq += __shfl_xor(sq, m, 32);
        float rstd = rsqrtf(sq * (1.0f/32.0f) + 1e-5f);
        s_ctx[row][l] = d * rstd * att_ln_w[l] + att_ln_b[l];
    }
    __syncthreads();

    // ---- phase 6: non_emb (t<128) / sp_emb (t>=128) -> s_x (bf16) ----
    if (t < 128) {
        float wreg[NAUG];
        #pragma unroll
        for (int j = 0; j < NAUG; ++j) wreg[j] = non_W[t * NAUG + j];
        float b = non_b[t];
        for (int row = 0; row < NROWS; ++row) {
            float acc = b;
            #pragma unroll
            for (int j = 0; j < NAUG; ++j) acc += wreg[j] * s_na[row][j];
            s_x[row][t] = f32_to_bf16(fmaxf(acc, 0.0f));
        }
    } else {
        const int o = t - 128;
        float w0 = spfb_W[o*3+0], w1 = spfb_W[o*3+1], w2 = spfb_W[o*3+2];
        float bfb = spfb_b[o];
        float wreg[32];
        #pragma unroll
        for (int k = 0; k < 32; ++k) wreg[k] = spatial_W[o * 32 + k];
        float bsp = spatial_b[o];
        float alpha = 1.0f / (1.0f + __expf(-sp_gate_p[0]));
        for (int row = 0; row < NROWS; ++row) {
            float fb = fmaxf(bfb + w0*s_na[row][11] + w1*s_na[row][12] + w2*s_na[row][13], 0.0f);
            float at = bsp;
            #pragma unroll
            for (int k = 0; k < 32; ++k) at += wreg[k] * s_ctx[row][k];
            at = fmaxf(at, 0.0f);
            s_x[row][128 + o] = f32_to_bf16(alpha * at + (1.0f - alpha) * fb);
        }
    }
    __syncthreads();

    // ---- phase 7: fuse GEMM via MFMA 16x16x32 bf16 ----
    // A = s_x [16 rows x 256], B^T = fuse_W (pre-swizzled), D[16 x 256]
    {
        const int wid  = t >> 6;       // wave 0..3 -> col tiles wid*4 .. wid*4+3
        const int wl   = t & 63;
        const int arow = wl & 15;
        const int kg   = wl >> 4;
        f32x4 acc[4];
        #pragma unroll
        for (int i = 0; i < 4; ++i) acc[i] = f32x4{0.f, 0.f, 0.f, 0.f};
        #pragma unroll
        for (int ks = 0; ks < 8; ++ks) {
            bf16x8 a = *reinterpret_cast<const bf16x8*>(&s_x[arow][ks * 32 + kg * 8]);
            #pragma unroll
            for (int i = 0; i < 4; ++i) {
                const int ct = wid * 4 + i;
                bf16x8 bfr = *reinterpret_cast<const bf16x8*>(
                    Wb + (((ks * 16 + ct) * 64) + wl) * 8);
                acc[i] = __builtin_amdgcn_mfma_f32_16x16x32_bf16(a, bfr, acc[i], 0, 0, 0);
            }
        }
        #pragma unroll
        for (int i = 0; i < 4; ++i) {
            const int ct  = wid * 4 + i;
            const int col = ct * 16 + arow;
            const float bias = fuse_b[col];
            #pragma unroll
            for (int r = 0; r < 4; ++r) {
                const int row = kg * 4 + r;
                s_y[row][col] = fmaxf(acc[i][r] + bias, 0.0f);
            }
        }
    }
    __syncthreads();

    // ---- phase 8: LN256 stats per row ----
    for (int rr = 0; rr < 2; ++rr) {
        const int row = g + 8 * rr;
        float v[8], sm = 0.0f;
        #pragma unroll
        for (int m = 0; m < 8; ++m) { v[m] = s_y[row][l + 32 * m]; sm += v[m]; }
        for (int m = 16; m >= 1; m >>= 1) sm += __shfl_xor(sm, m, 32);
        float mean = sm * (1.0f/256.0f);
        float sq = 0.0f;
        #pragma unroll
        for (int m = 0; m < 8; ++m) { float d = v[m] - mean; sq += d * d; }
        for (int m = 16; m >= 1; m >>= 1) sq += __shfl_xor(sq, m, 32);
        float rstd = rsqrtf(sq * (1.0f/256.0f) + 1e-5f);
        if (l == 0) { s_mr[row][0] = mean; s_mr[row][1] = rstd; }
    }
    __syncthreads();

    // ---- phase 9: outputs ----
    {
        const float lw = ln_w[t], lb = ln_b[t];
        for (int row = 0; row < NROWS; ++row) {
            float v = s_y[row][t];
            out_x[(rowbase + row) * EMBD + t] = (v - s_mr[row][0]) * s_mr[row][1] * lw + lb;
        }
        if (t < NROWS * 2)
            out_tf[rowbase * 2 + t] = ((const float*)s_tf2)[t];
    }
}

extern "C" void kernel_launch(void* const* d_in, const int* in_sizes, int n_in,
                              void* d_out, int out_size, void* d_ws, size_t ws_size,
                              hipStream_t stream) {
    const float* state     = (const float*)d_in[0];
    const float* token_W   = (const float*)d_in[1];
    const float* token_b   = (const float*)d_in[2];
    const float* query_W   = (const float*)d_in[3];
    const float* query_b   = (const float*)d_in[4];
    const float* rbs       = (const float*)d_in[5];
    const float* vbias     = (const float*)d_in[6];
    const float* ivbias    = (const float*)d_in[7];
    const float* att_ln_w  = (const float*)d_in[8];
    const float* att_ln_b  = (const float*)d_in[9];
    const float* non_W     = (const float*)d_in[10];
    const float* non_b     = (const float*)d_in[11];
    const float* spfb_W    = (const float*)d_in[12];
    const float* spfb_b    = (const float*)d_in[13];
    const float* sp_gate   = (const float*)d_in[14];
    const float* spatial_W = (const float*)d_in[15];
    const float* spatial_b = (const float*)d_in[16];
    const float* fuse_W    = (const float*)d_in[17];
    const float* fuse_b    = (const float*)d_in[18];
    const float* ln_w      = (const float*)d_in[19];
    const float* ln_b      = (const float*)d_in[20];

    float* out_x  = (float*)d_out;
    float* out_tf = out_x + (size_t)BH * EMBD;

    unsigned short* Wb = (unsigned short*)d_ws;   // 256*256 bf16 = 128 KiB

    hipLaunchKernelGGL(prep_w_kernel, dim3(32), dim3(256), 0, stream, fuse_W, Wb);

    hipLaunchKernelGGL(att_state_enc_kernel, dim3(NBLOCKS), dim3(NTHREADS), 0, stream,
        state, token_W, token_b, query_W, query_b, rbs, vbias, ivbias,
        att_ln_w, att_ln_b, non_W, non_b, spfb_W, spfb_b, sp_gate,
        spatial_W, spatial_b, Wb, fuse_b, ln_w, ln_b,
        out_x, out_tf);
}

// Round 3
// 69.773 us; speedup vs baseline: 4.7377x; 3.3250x over previous
//
#include <hip/hip_runtime.h>

// Problem constants
#define BH      65536     // B*H
#define DSTATE  75
#define EMBD    256
#define NROWS   16
#define NTHREADS 256
#define NBLOCKS (BH / NROWS)

typedef short bf16x8 __attribute__((ext_vector_type(8)));
typedef float f32x4  __attribute__((ext_vector_type(4)));

__device__ __forceinline__ unsigned short f32_to_bf16(float f) {
    union { float f; unsigned int u; } v; v.f = f;
    unsigned int u = v.u;
    u = u + 0x7FFFu + ((u >> 16) & 1u);
    return (unsigned short)(u >> 16);
}
__device__ __forceinline__ unsigned int pack2(float a, float b) {
    return (unsigned int)f32_to_bf16(a) | ((unsigned int)f32_to_bf16(b) << 16);
}
__device__ __forceinline__ float bf_lo(unsigned int w) {
    union { unsigned int u; float f; } c; c.u = w << 16; return c.f;
}
__device__ __forceinline__ float bf_hi(unsigned int w) {
    union { unsigned int u; float f; } c; c.u = w & 0xFFFF0000u; return c.f;
}

// ---- prep: swizzle fuse_W (256x256), non_W (128x17 pad32), spatial_W (128x32)
// into bf16 MFMA B-fragments.
// Fragment: n = ct*16 + (wl&15), k = ks*32 + (wl>>4)*8 + j, B[k][n] = W[n][k].
__global__ __launch_bounds__(256) void prep_w_kernel(
    const float* __restrict__ fuse_W, const float* __restrict__ non_W,
    const float* __restrict__ spatial_W, unsigned short* __restrict__ ws)
{
    int id = blockIdx.x * 256 + threadIdx.x;
    if (id < 8192) {                       // fuse: 8 ks * 16 ct * 64 wl
        int wl = id & 63, ct = (id >> 6) & 15, ks = id >> 10;
        int n = ct * 16 + (wl & 15);
        int k0 = ks * 32 + (wl >> 4) * 8;
        const float* src = fuse_W + n * 256 + k0;
        float4 a = *reinterpret_cast<const float4*>(src);
        float4 b = *reinterpret_cast<const float4*>(src + 4);
        uint4 o = make_uint4(pack2(a.x, a.y), pack2(a.z, a.w),
                             pack2(b.x, b.y), pack2(b.z, b.w));
        reinterpret_cast<uint4*>(ws)[id] = o;
    } else if (id < 8704) {                // non_W: 8 ct * 64 wl, K pad 17->32
        int i = id - 8192;
        int wl = i & 63, ct = i >> 6;
        int n = ct * 16 + (wl & 15);
        int k0 = (wl >> 4) * 8;
        float v[8];
        #pragma unroll
        for (int j = 0; j < 8; ++j) {
            int k = k0 + j;
            v[j] = (k < 17) ? non_W[n * 17 + k] : 0.0f;
        }
        uint4 o = make_uint4(pack2(v[0], v[1]), pack2(v[2], v[3]),
                             pack2(v[4], v[5]), pack2(v[6], v[7]));
        reinterpret_cast<uint4*>(ws)[8192 + i] = o;
    } else if (id < 9216) {                // spatial_W: 8 ct * 64 wl, K=32
        int i = id - 8704;
        int wl = i & 63, ct = i >> 6;
        int n = ct * 16 + (wl & 15);
        int k0 = (wl >> 4) * 8;
        const float* src = spatial_W + n * 32 + k0;
        float4 a = *reinterpret_cast<const float4*>(src);
        float4 b = *reinterpret_cast<const float4*>(src + 4);
        uint4 o = make_uint4(pack2(a.x, a.y), pack2(a.z, a.w),
                             pack2(b.x, b.y), pack2(b.z, b.w));
        reinterpret_cast<uint4*>(ws)[8704 + i] = o;
    }
}

__global__ __launch_bounds__(256, 4) void att_state_enc_kernel(
    const float* __restrict__ state,
    const float* __restrict__ token_W, const float* __restrict__ token_b,
    const float* __restrict__ query_W, const float* __restrict__ query_b,
    const float* __restrict__ rbs_p, const float* __restrict__ vb_p, const float* __restrict__ ivb_p,
    const float* __restrict__ att_ln_w, const float* __restrict__ att_ln_b,
    const float* __restrict__ non_b,
    const float* __restrict__ spfb_W, const float* __restrict__ spfb_b,
    const float* __restrict__ sp_gate_p,
    const float* __restrict__ spatial_b,
    const unsigned short* __restrict__ Wf, const unsigned short* __restrict__ Wn,
    const unsigned short* __restrict__ Ws,
    const float* __restrict__ fuse_b,
    const float* __restrict__ ln_w, const float* __restrict__ ln_b,
    float* __restrict__ out_x, float* __restrict__ out_tf)
{
    __shared__ float  s_na[NROWS][20];                        // f32 non_aug (stats for fb)
    __shared__ __align__(16) unsigned short s_na_bf[NROWS][32];
    __shared__ __align__(16) unsigned short s_ctx_bf[NROWS][32];
    __shared__ __align__(16) unsigned short s_q_bf[NROWS][32];
    __shared__ __align__(16) uint2 s_pack[NROWS][32];         // (w,sec | dif,vld) bf16x4
    __shared__ __align__(16) unsigned short s_x[NROWS][264];  // fuse input bf16
    __shared__ __align__(16) float2 s_part[NROWS][4];         // LN partials per wave
    __shared__ float  s_tf[NROWS * 2];

    const int t = threadIdx.x;
    const int g = t >> 5;          // 32-lane group
    const int l = t & 31;
    const long rowbase = (long)blockIdx.x * NROWS;

    const float rbs = rbs_p[0];
    const float vb  = vb_p[0];
    const float ivb = ivb_p[0];

    // ================= per-row phases (wave-local, no barriers) =================
    for (int rr = 0; rr < 2; ++rr) {
        const int row = g + 8 * rr;
        const long gb = (rowbase + row) * DSTATE;

        // -- phase 2: loads + stats --
        float sec = state[gb + l];
        float dif = state[gb + 32 + l];
        float nl  = (l < 11) ? state[gb + 64 + l] : 0.0f;
        float vld = (sec < 0.95f) ? 1.0f : 0.0f;
        float da  = fabsf(dif);
        float mn = sec, sm = sec, vs = vld, ds = da, dmx = da;
        for (int m = 16; m >= 1; m >>= 1) {
            mn  = fminf(mn, __shfl_xor(mn, m, 32));
            sm += __shfl_xor(sm, m, 32);
            vs += __shfl_xor(vs, m, 32);
            ds += __shfl_xor(ds, m, 32);
            dmx = fmaxf(dmx, __shfl_xor(dmx, m, 32));
        }
        const float min_r = mn, mean_r = sm * (1.0f/32.0f), vr = vs * (1.0f/32.0f);
        const float dam = ds * (1.0f/32.0f), dax = dmx;
        const float dyaw = fminf(fabsf(__shfl(nl, 8, 32)), 1.0f);

        float naval = nl;
        if (l == 11) naval = min_r;
        else if (l == 12) naval = mean_r;
        else if (l == 13) naval = vr;
        else if (l == 14) naval = dam;
        else if (l == 15) naval = dax;
        else if (l == 16) naval = dyaw;
        if (l < 17) s_na[row][l] = naval;
        s_na_bf[row][l] = (l < 17) ? f32_to_bf16(naval) : (unsigned short)0;
        if (l == 0) { s_tf[row * 2] = fminf(dam, 1.0f); s_tf[row * 2 + 1] = dyaw; }

        // -- phase 3: q = relu(query_W @ na) ; lane = feature --
        {
            uint4 n01 = *reinterpret_cast<const uint4*>(&s_na_bf[row][0]);
            uint4 n23 = *reinterpret_cast<const uint4*>(&s_na_bf[row][8]);
            float na0 = bf_lo(n01.x), na1 = bf_hi(n01.x), na2 = bf_lo(n01.y), na3 = bf_hi(n01.y);
            float na4 = bf_lo(n01.z), na5 = bf_hi(n01.z), na6 = bf_lo(n01.w), na7 = bf_hi(n01.w);
            float na8 = bf_lo(n23.x), na9 = bf_hi(n23.x), na10 = bf_lo(n23.y);
            const float* qw = query_W + l * 17;
            float acc = query_b[l];
            acc += qw[0]*na0 + qw[1]*na1 + qw[2]*na2 + qw[3]*na3 + qw[4]*na4
                 + qw[5]*na5 + qw[6]*na6 + qw[7]*na7 + qw[8]*na8 + qw[9]*na9 + qw[10]*na10;
            acc += qw[11]*min_r + qw[12]*mean_r + qw[13]*vr + qw[14]*dam + qw[15]*dax + qw[16]*dyaw;
            s_q_bf[row][l] = f32_to_bf16(fmaxf(acc, 0.0f));
        }

        // -- phase 4: score + softmax ; lane = sector --
        {
            unsigned int qw[16];
            *reinterpret_cast<uint4*>(&qw[0])  = *reinterpret_cast<const uint4*>(&s_q_bf[row][0]);
            *reinterpret_cast<uint4*>(&qw[4])  = *reinterpret_cast<const uint4*>(&s_q_bf[row][8]);
            *reinterpret_cast<uint4*>(&qw[8])  = *reinterpret_cast<const uint4*>(&s_q_bf[row][16]);
            *reinterpret_cast<uint4*>(&qw[12]) = *reinterpret_cast<const uint4*>(&s_q_bf[row][24]);
            float acc = 0.0f;
            #pragma unroll
            for (int k = 0; k < 32; ++k) {
                // uniform scalar loads (SMEM pipe)
                float tok = fmaxf(token_b[k] + token_W[3*k]*sec + token_W[3*k+1]*dif
                                  + token_W[3*k+2]*vld, 0.0f);
                float qk = (k & 1) ? bf_hi(qw[k >> 1]) : bf_lo(qw[k >> 1]);
                acc += tok * qk;
            }
            float score = acc * 0.17677669529663687f
                        + rbs * (1.0f - sec) + vb * vld + ivb * (1.0f - vld);
            float mx = score;
            for (int m = 16; m >= 1; m >>= 1) mx = fmaxf(mx, __shfl_xor(mx, m, 32));
            float e = __expf(score - mx);
            float se = e;
            for (int m = 16; m >= 1; m >>= 1) se += __shfl_xor(se, m, 32);
            float w = __fdividef(e, se);
            s_pack[row][l] = make_uint2(pack2(w, sec), pack2(dif, vld));
        }

        // -- phase 5: ctx + LN32 ; lane = feature --
        {
            const float tb  = token_b[l];
            const float tw0 = token_W[3*l], tw1 = token_W[3*l+1], tw2 = token_W[3*l+2];
            float acc = 0.0f;
            #pragma unroll
            for (int i = 0; i < 16; ++i) {
                uint4 pk = *reinterpret_cast<const uint4*>(&s_pack[row][i * 2]);
                float wA = bf_lo(pk.x), sA = bf_hi(pk.x), dA = bf_lo(pk.y), vA = bf_hi(pk.y);
                float wB = bf_lo(pk.z), sB = bf_hi(pk.z), dB = bf_lo(pk.w), vB = bf_hi(pk.w);
                acc += wA * fmaxf(tb + tw0*sA + tw1*dA + tw2*vA, 0.0f);
                acc += wB * fmaxf(tb + tw0*sB + tw1*dB + tw2*vB, 0.0f);
            }
            float smv = acc;
            for (int m = 16; m >= 1; m >>= 1) smv += __shfl_xor(smv, m, 32);
            float mean = smv * (1.0f/32.0f);
            float d = acc - mean;
            float sq = d * d;
            for (int m = 16; m >= 1; m >>= 1) sq += __shfl_xor(sq, m, 32);
            float rstd = rsqrtf(sq * (1.0f/32.0f) + 1e-5f);
            float ctx = d * rstd * att_ln_w[l] + att_ln_b[l];
            s_ctx_bf[row][l] = f32_to_bf16(ctx);
        }
    }
    __syncthreads();   // BARRIER 1

    // ================= phase B: non_emb + sp_emb via MFMA =================
    {
        const int wid = t >> 6, wl = t & 63;
        const int arow = wl & 15, kg = wl >> 4;

        if (t < 32) out_tf[rowbase * 2 + t] = s_tf[t];

        const float alpha = 1.0f / (1.0f + __expf(-sp_gate_p[0]));
        // fb stats for this cluster's 4 rows
        float mnr[4], mer[4], vrr[4];
        #pragma unroll
        for (int r = 0; r < 4; ++r) {
            const int row = kg * 4 + r;
            mnr[r] = s_na[row][11]; mer[r] = s_na[row][12]; vrr[r] = s_na[row][13];
        }
        bf16x8 a_na  = *reinterpret_cast<const bf16x8*>(&s_na_bf[arow][kg * 8]);
        bf16x8 a_ctx = *reinterpret_cast<const bf16x8*>(&s_ctx_bf[arow][kg * 8]);

        #pragma unroll
        for (int tt = 0; tt < 2; ++tt) {
            const int ct = wid * 2 + tt;          // 0..7
            const int col = ct * 16 + arow;       // 0..127
            bf16x8 bN = *reinterpret_cast<const bf16x8*>(Wn + ((ct * 64) + wl) * 8);
            bf16x8 bS = *reinterpret_cast<const bf16x8*>(Ws + ((ct * 64) + wl) * 8);
            f32x4 accN = __builtin_amdgcn_mfma_f32_16x16x32_bf16(a_na,  bN, f32x4{0.f,0.f,0.f,0.f}, 0,0,0);
            f32x4 accS = __builtin_amdgcn_mfma_f32_16x16x32_bf16(a_ctx, bS, f32x4{0.f,0.f,0.f,0.f}, 0,0,0);
            const float nb = non_b[col], sb = spatial_b[col];
            const float w0 = spfb_W[col*3], w1 = spfb_W[col*3+1], w2 = spfb_W[col*3+2];
            const float fbb = spfb_b[col];
            #pragma unroll
            for (int r = 0; r < 4; ++r) {
                const int row = kg * 4 + r;
                float ne = fmaxf(accN[r] + nb, 0.0f);
                float sa = fmaxf(accS[r] + sb, 0.0f);
                float fb = fmaxf(fbb + w0*mnr[r] + w1*mer[r] + w2*vrr[r], 0.0f);
                float sp = alpha * sa + (1.0f - alpha) * fb;
                s_x[row][col]       = f32_to_bf16(ne);
                s_x[row][128 + col] = f32_to_bf16(sp);
            }
        }
    }
    __syncthreads();   // BARRIER 2

    // ================= phase C: fuse GEMM (MFMA) + LN partials =================
    const int wid = t >> 6, wl = t & 63;
    const int arow = wl & 15, kg = wl >> 4;
    float v[4][4];
    {
        f32x4 acc[4];
        #pragma unroll
        for (int i = 0; i < 4; ++i) acc[i] = f32x4{0.f, 0.f, 0.f, 0.f};
        #pragma unroll
        for (int ks = 0; ks < 8; ++ks) {
            bf16x8 a = *reinterpret_cast<const bf16x8*>(&s_x[arow][ks * 32 + kg * 8]);
            #pragma unroll
            for (int i = 0; i < 4; ++i) {
                const int ct = wid * 4 + i;
                bf16x8 b = *reinterpret_cast<const bf16x8*>(Wf + (((ks * 16 + ct) * 64) + wl) * 8);
                acc[i] = __builtin_amdgcn_mfma_f32_16x16x32_bf16(a, b, acc[i], 0, 0, 0);
            }
        }
        float psum[4] = {0.f, 0.f, 0.f, 0.f};
        float psq[4]  = {0.f, 0.f, 0.f, 0.f};
        #pragma unroll
        for (int i = 0; i < 4; ++i) {
            const int col = (wid * 4 + i) * 16 + arow;
            const float bias = fuse_b[col];
            #pragma unroll
            for (int r = 0; r < 4; ++r) {
                float x = fmaxf(acc[i][r] + bias, 0.0f);
                v[i][r] = x;
                psum[r] += x;
                psq[r]  += x * x;
            }
        }
        #pragma unroll
        for (int r = 0; r < 4; ++r) {
            for (int m = 8; m >= 1; m >>= 1) {
                psum[r] += __shfl_xor(psum[r], m, 16);
                psq[r]  += __shfl_xor(psq[r],  m, 16);
            }
        }
        if (arow == 0) {
            #pragma unroll
            for (int r = 0; r < 4; ++r)
                s_part[kg * 4 + r][wid] = make_float2(psum[r], psq[r]);
        }
    }
    __syncthreads();   // BARRIER 3

    // ================= phase D: LN + store =================
    {
        float lwv[4], lbv[4];
        #pragma unroll
        for (int i = 0; i < 4; ++i) {
            const int col = (wid * 4 + i) * 16 + arow;
            lwv[i] = ln_w[col]; lbv[i] = ln_b[col];
        }
        #pragma unroll
        for (int r = 0; r < 4; ++r) {
            const int row = kg * 4 + r;
            float4 pa = *reinterpret_cast<const float4*>(&s_part[row][0]);
            float4 pb = *reinterpret_cast<const float4*>(&s_part[row][2]);
            float sum = pa.x + pa.z + pb.x + pb.z;
            float sq  = pa.y + pa.w + pb.y + pb.w;
            float mean = sum * (1.0f/256.0f);
            float var  = sq * (1.0f/256.0f) - mean * mean;
            float rstd = rsqrtf(var + 1e-5f);
            const long obase = (rowbase + row) * EMBD;
            #pragma unroll
            for (int i = 0; i < 4; ++i) {
                const int col = (wid * 4 + i) * 16 + arow;
                out_x[obase + col] = (v[i][r] - mean) * rstd * lwv[i] + lbv[i];
            }
        }
    }
}

extern "C" void kernel_launch(void* const* d_in, const int* in_sizes, int n_in,
                              void* d_out, int out_size, void* d_ws, size_t ws_size,
                              hipStream_t stream) {
    const float* state     = (const float*)d_in[0];
    const float* token_W   = (const float*)d_in[1];
    const float* token_b   = (const float*)d_in[2];
    const float* query_W   = (const float*)d_in[3];
    const float* query_b   = (const float*)d_in[4];
    const float* rbs       = (const float*)d_in[5];
    const float* vbias     = (const float*)d_in[6];
    const float* ivbias    = (const float*)d_in[7];
    const float* att_ln_w  = (const float*)d_in[8];
    const float* att_ln_b  = (const float*)d_in[9];
    const float* non_W     = (const float*)d_in[10];
    const float* non_b     = (const float*)d_in[11];
    const float* spfb_W    = (const float*)d_in[12];
    const float* spfb_b    = (const float*)d_in[13];
    const float* sp_gate   = (const float*)d_in[14];
    const float* spatial_W = (const float*)d_in[15];
    const float* spatial_b = (const float*)d_in[16];
    const float* fuse_W    = (const float*)d_in[17];
    const float* fuse_b    = (const float*)d_in[18];
    const float* ln_w      = (const float*)d_in[19];
    const float* ln_b      = (const float*)d_in[20];

    float* out_x  = (float*)d_out;
    float* out_tf = out_x + (size_t)BH * EMBD;

    unsigned short* wsu = (unsigned short*)d_ws;
    const unsigned short* Wf = wsu;               // 65536 bf16
    const unsigned short* Wn = wsu + 65536;       // 4096 bf16
    const unsigned short* Ws = wsu + 65536 + 4096;// 4096 bf16

    hipLaunchKernelGGL(prep_w_kernel, dim3(36), dim3(256), 0, stream,
                       fuse_W, non_W, spatial_W, wsu);

    hipLaunchKernelGGL(att_state_enc_kernel, dim3(NBLOCKS), dim3(NTHREADS), 0, stream,
        state, token_W, token_b, query_W, query_b, rbs, vbias, ivbias,
        att_ln_w, att_ln_b, non_b, spfb_W, spfb_b, sp_gate, spatial_b,
        Wf, Wn, Ws, fuse_b, ln_w, ln_b, out_x, out_tf);
}

// Round 4
// 67.954 us; speedup vs baseline: 4.8645x; 1.0268x over previous
//
#include <hip/hip_runtime.h>

// Problem constants
#define BH      65536     // B*H
#define DSTATE  75
#define EMBD    256
#define NROWS   16
#define NTHREADS 256
#define NBLOCKS (BH / NROWS)

typedef _Float16 h2    __attribute__((ext_vector_type(2)));
typedef _Float16 f16x8 __attribute__((ext_vector_type(8)));
typedef float    f32x4 __attribute__((ext_vector_type(4)));

__device__ __forceinline__ h2 u2h(unsigned int u) {
    union { unsigned int u; h2 h; } c; c.u = u; return c.h;
}
__device__ __forceinline__ unsigned int packh2(float a, float b) {
    union { h2 h; unsigned int u; } c;
    c.h = h2{(_Float16)a, (_Float16)b}; return c.u;
}
__device__ __forceinline__ float fdot2(h2 a, h2 b, float c) {
#if __has_builtin(__builtin_amdgcn_fdot2)
    return __builtin_amdgcn_fdot2(a, b, c, false);
#else
    return c + (float)a[0] * (float)b[0] + (float)a[1] * (float)b[1];
#endif
}
__device__ __forceinline__ h2 pkfma(h2 a, h2 b, h2 c) {
#if __has_builtin(__builtin_elementwise_fma)
    return __builtin_elementwise_fma(a, b, c);
#else
    return a * b + c;
#endif
}

// ---- prep: swizzle fuse_W (256x256), non_W (128x17 pad32), spatial_W (128x32)
// into f16 MFMA B-fragments; plus f16-pair tables for query_W and token params.
// Fragment: n = ct*16 + (wl&15), k = ks*32 + (wl>>4)*8 + j, B[k][n] = W[n][k].
__global__ __launch_bounds__(256) void prep_w_kernel(
    const float* __restrict__ fuse_W, const float* __restrict__ non_W,
    const float* __restrict__ spatial_W, const float* __restrict__ query_W,
    const float* __restrict__ token_W, const float* __restrict__ token_b,
    unsigned short* __restrict__ ws)
{
    int id = blockIdx.x * 256 + threadIdx.x;
    if (id < 8192) {                       // fuse: 8 ks * 16 ct * 64 wl
        int wl = id & 63, ct = (id >> 6) & 15, ks = id >> 10;
        int n = ct * 16 + (wl & 15);
        int k0 = ks * 32 + (wl >> 4) * 8;
        const float* src = fuse_W + n * 256 + k0;
        float4 a = *reinterpret_cast<const float4*>(src);
        float4 b = *reinterpret_cast<const float4*>(src + 4);
        uint4 o = make_uint4(packh2(a.x, a.y), packh2(a.z, a.w),
                             packh2(b.x, b.y), packh2(b.z, b.w));
        reinterpret_cast<uint4*>(ws)[id] = o;
    } else if (id < 8704) {                // non_W: 8 ct * 64 wl, K pad 17->32
        int i = id - 8192;
        int wl = i & 63, ct = i >> 6;
        int n = ct * 16 + (wl & 15);
        int k0 = (wl >> 4) * 8;
        float v[8];
        #pragma unroll
        for (int j = 0; j < 8; ++j) {
            int k = k0 + j;
            v[j] = (k < 17) ? non_W[n * 17 + k] : 0.0f;
        }
        uint4 o = make_uint4(packh2(v[0], v[1]), packh2(v[2], v[3]),
                             packh2(v[4], v[5]), packh2(v[6], v[7]));
        reinterpret_cast<uint4*>(ws)[8192 + i] = o;
    } else if (id < 9216) {                // spatial_W: 8 ct * 64 wl, K=32
        int i = id - 8704;
        int wl = i & 63, ct = i >> 6;
        int n = ct * 16 + (wl & 15);
        int k0 = (wl >> 4) * 8;
        const float* src = spatial_W + n * 32 + k0;
        float4 a = *reinterpret_cast<const float4*>(src);
        float4 b = *reinterpret_cast<const float4*>(src + 4);
        uint4 o = make_uint4(packh2(a.x, a.y), packh2(a.z, a.w),
                             packh2(b.x, b.y), packh2(b.z, b.w));
        reinterpret_cast<uint4*>(ws)[8704 + i] = o;
    } else if (id < 9728) {                // qWh: 32 feat * 16 pairs (17 -> pad 32)
        int i = id - 9216;
        int feat = i >> 4, j = i & 15;
        int k0 = 2 * j, k1 = 2 * j + 1;
        float a = (k0 < 17) ? query_W[feat * 17 + k0] : 0.0f;
        float b = (k1 < 17) ? query_W[feat * 17 + k1] : 0.0f;
        unsigned int* qWh = reinterpret_cast<unsigned int*>(ws + 73728);
        qWh[i] = packh2(a, b);
    } else if (id < 9856) {                // TWb broadcast tables: 4 tables * 32
        int i = id - 9728;
        int tbl = i >> 5, k = i & 31;
        float v = (tbl == 0) ? token_W[3 * k]
                : (tbl == 1) ? token_W[3 * k + 1]
                : (tbl == 2) ? token_W[3 * k + 2]
                : token_b[k];
        unsigned int* TWb = reinterpret_cast<unsigned int*>(ws + 73728) + 512;
        TWb[i] = packh2(v, v);
    }
}

__global__ __launch_bounds__(256, 4) void att_state_enc_kernel(
    const float* __restrict__ state,
    const float* __restrict__ token_W, const float* __restrict__ token_b,
    const float* __restrict__ query_b,
    const float* __restrict__ rbs_p, const float* __restrict__ vb_p, const float* __restrict__ ivb_p,
    const float* __restrict__ att_ln_w, const float* __restrict__ att_ln_b,
    const float* __restrict__ non_b,
    const float* __restrict__ spfb_W, const float* __restrict__ spfb_b,
    const float* __restrict__ sp_gate_p,
    const float* __restrict__ spatial_b,
    const unsigned short* __restrict__ Wf, const unsigned short* __restrict__ Wn,
    const unsigned short* __restrict__ Ws,
    const unsigned int* __restrict__ qWh, const unsigned int* __restrict__ TWb,
    const float* __restrict__ fuse_b,
    const float* __restrict__ ln_w, const float* __restrict__ ln_b,
    float* __restrict__ out_x, float* __restrict__ out_tf)
{
    __shared__ float  s_fb[NROWS][4];                          // min_r, mean_r, vr
    __shared__ __align__(16) _Float16 s_na_h[NROWS][32];       // non_aug f16 (pad 0)
    __shared__ __align__(16) _Float16 s_ctx_h[NROWS][32];
    __shared__ __align__(16) float s_q[NROWS][32];             // q f32
    __shared__ __align__(16) uint4 s_p4[NROWS][16];            // (w2,s2,d2,v2) f16 pairs
    __shared__ __align__(16) _Float16 s_x[NROWS][264];         // fuse input f16
    __shared__ __align__(16) float2 s_part[NROWS][4];
    __shared__ float  s_tf[NROWS * 2];

    const int t = threadIdx.x;
    const int g = t >> 5;
    const int l = t & 31;
    const long rowbase = (long)blockIdx.x * NROWS;

    const float rbs = rbs_p[0];
    const float vb  = vb_p[0];
    const float ivb = ivb_p[0];

    // hoisted per-lane tables
    const float qb = query_b[l];
    const uint4* qwp = reinterpret_cast<const uint4*>(qWh + l * 16);
    const uint4 qw0 = qwp[0], qw1 = qwp[1], qw2 = qwp[2];      // pairs 0..11 (use 0..8)
    const h2 tw0b = u2h(TWb[l]);
    const h2 tw1b = u2h(TWb[32 + l]);
    const h2 tw2b = u2h(TWb[64 + l]);
    const h2 tbb  = u2h(TWb[96 + l]);
    const h2 zero2 = h2{(_Float16)0.0f, (_Float16)0.0f};

    // ================= per-row phases (wave-local) =================
    for (int rr = 0; rr < 2; ++rr) {
        const int row = g + 8 * rr;
        const long gb = (rowbase + row) * DSTATE;

        // -- phase 2: loads + stats --
        float sec = state[gb + l];
        float dif = state[gb + 32 + l];
        float nl  = (l < 11) ? state[gb + 64 + l] : 0.0f;
        float vld = (sec < 0.95f) ? 1.0f : 0.0f;
        float da  = fabsf(dif);
        float mn = sec, sm = sec, vs = vld, ds = da, dmx = da;
        for (int m = 16; m >= 1; m >>= 1) {
            mn  = fminf(mn, __shfl_xor(mn, m, 32));
            sm += __shfl_xor(sm, m, 32);
            vs += __shfl_xor(vs, m, 32);
            ds += __shfl_xor(ds, m, 32);
            dmx = fmaxf(dmx, __shfl_xor(dmx, m, 32));
        }
        const float min_r = mn, mean_r = sm * (1.0f/32.0f), vr = vs * (1.0f/32.0f);
        const float dam = ds * (1.0f/32.0f), dax = dmx;
        const float dyaw = fminf(fabsf(__shfl(nl, 8, 32)), 1.0f);

        float naval = 0.0f;
        if (l < 11)       naval = nl;
        else if (l == 11) naval = min_r;
        else if (l == 12) naval = mean_r;
        else if (l == 13) naval = vr;
        else if (l == 14) naval = dam;
        else if (l == 15) naval = dax;
        else if (l == 16) naval = dyaw;
        s_na_h[row][l] = (_Float16)naval;
        if (l < 3) s_fb[row][l] = (l == 0) ? min_r : (l == 1) ? mean_r : vr;
        if (l == 0) { s_tf[row * 2] = fminf(dam, 1.0f); s_tf[row * 2 + 1] = dyaw; }

        // -- phase 3: q = relu(query_W @ na), via f16 dot2; lane = feature --
        {
            const uint4* nap = reinterpret_cast<const uint4*>(&s_na_h[row][0]);
            uint4 n0 = nap[0], n1 = nap[1], n2 = nap[2];
            float acc = qb;
            acc = fdot2(u2h(qw0.x), u2h(n0.x), acc);
            acc = fdot2(u2h(qw0.y), u2h(n0.y), acc);
            acc = fdot2(u2h(qw0.z), u2h(n0.z), acc);
            acc = fdot2(u2h(qw0.w), u2h(n0.w), acc);
            acc = fdot2(u2h(qw1.x), u2h(n1.x), acc);
            acc = fdot2(u2h(qw1.y), u2h(n1.y), acc);
            acc = fdot2(u2h(qw1.z), u2h(n1.z), acc);
            acc = fdot2(u2h(qw1.w), u2h(n1.w), acc);
            acc = fdot2(u2h(qw2.x), u2h(n2.x), acc);
            s_q[row][l] = fmaxf(acc, 0.0f);
        }

        // -- phase 4: score + softmax ; lane = sector --
        {
            float4 qv[8];
            #pragma unroll
            for (int j = 0; j < 8; ++j)
                qv[j] = *reinterpret_cast<const float4*>(&s_q[row][j * 4]);
            const float* qf = reinterpret_cast<const float*>(qv);
            float acc = 0.0f;
            #pragma unroll
            for (int k = 0; k < 32; ++k) {
                float tok = fmaxf(token_b[k] + token_W[3*k]*sec + token_W[3*k+1]*dif
                                  + token_W[3*k+2]*vld, 0.0f);
                acc += tok * qf[k];
            }
            float score = acc * 0.17677669529663687f
                        + rbs * (1.0f - sec) + vb * vld + ivb * (1.0f - vld);
            float mx = score;
            for (int m = 16; m >= 1; m >>= 1) mx = fmaxf(mx, __shfl_xor(mx, m, 32));
            float e = __expf(score - mx);
            float se = e;
            for (int m = 16; m >= 1; m >>= 1) se += __shfl_xor(se, m, 32);
            float w = __fdividef(e, se);
            // pack (w,sec,dif,vld) as f16 halves of the pair slot
            _Float16* pp = reinterpret_cast<_Float16*>(&s_p4[row][l >> 1]);
            const int e2 = l & 1;
            pp[0 + e2] = (_Float16)w;
            pp[2 + e2] = (_Float16)sec;
            pp[4 + e2] = (_Float16)dif;
            pp[6 + e2] = (_Float16)vld;
        }

        // -- phase 5: ctx + LN32 via packed f16 ; lane = feature --
        {
            float acc = 0.0f;
            #pragma unroll
            for (int i = 0; i < 16; ++i) {
                uint4 pk = s_p4[row][i];
                h2 w2 = u2h(pk.x), s2 = u2h(pk.y), d2 = u2h(pk.z), v2 = u2h(pk.w);
                h2 z = pkfma(v2, tw2b, tbb);
                z = pkfma(s2, tw0b, z);
                z = pkfma(d2, tw1b, z);
                z = __builtin_elementwise_max(z, zero2);
                acc = fdot2(w2, z, acc);
            }
            float smv = acc;
            for (int m = 16; m >= 1; m >>= 1) smv += __shfl_xor(smv, m, 32);
            float mean = smv * (1.0f/32.0f);
            float d = acc - mean;
            float sq = d * d;
            for (int m = 16; m >= 1; m >>= 1) sq += __shfl_xor(sq, m, 32);
            float rstd = rsqrtf(sq * (1.0f/32.0f) + 1e-5f);
            float ctx = d * rstd * att_ln_w[l] + att_ln_b[l];
            s_ctx_h[row][l] = (_Float16)ctx;
        }
    }
    __syncthreads();   // BARRIER 1

    // ================= phase B: non_emb + sp_emb via MFMA (f16) =================
    {
        const int wid = t >> 6, wl = t & 63;
        const int arow = wl & 15, kg = wl >> 4;

        if (t < 32) out_tf[rowbase * 2 + t] = s_tf[t];

        const float alpha = 1.0f / (1.0f + __expf(-sp_gate_p[0]));
        float mnr[4], mer[4], vrr[4];
        #pragma unroll
        for (int r = 0; r < 4; ++r) {
            const int row = kg * 4 + r;
            mnr[r] = s_fb[row][0]; mer[r] = s_fb[row][1]; vrr[r] = s_fb[row][2];
        }
        f16x8 a_na  = *reinterpret_cast<const f16x8*>(&s_na_h[arow][kg * 8]);
        f16x8 a_ctx = *reinterpret_cast<const f16x8*>(&s_ctx_h[arow][kg * 8]);

        #pragma unroll
        for (int tt = 0; tt < 2; ++tt) {
            const int ct = wid * 2 + tt;
            const int col = ct * 16 + arow;
            f16x8 bN = *reinterpret_cast<const f16x8*>(Wn + ((ct * 64) + wl) * 8);
            f16x8 bS = *reinterpret_cast<const f16x8*>(Ws + ((ct * 64) + wl) * 8);
            f32x4 accN = __builtin_amdgcn_mfma_f32_16x16x32_f16(a_na,  bN, f32x4{0.f,0.f,0.f,0.f}, 0,0,0);
            f32x4 accS = __builtin_amdgcn_mfma_f32_16x16x32_f16(a_ctx, bS, f32x4{0.f,0.f,0.f,0.f}, 0,0,0);
            const float nb = non_b[col], sb = spatial_b[col];
            const float w0 = spfb_W[col*3], w1 = spfb_W[col*3+1], w2 = spfb_W[col*3+2];
            const float fbb = spfb_b[col];
            #pragma unroll
            for (int r = 0; r < 4; ++r) {
                const int row = kg * 4 + r;
                float ne = fmaxf(accN[r] + nb, 0.0f);
                float sa = fmaxf(accS[r] + sb, 0.0f);
                float fb = fmaxf(fbb + w0*mnr[r] + w1*mer[r] + w2*vrr[r], 0.0f);
                float sp = alpha * sa + (1.0f - alpha) * fb;
                s_x[row][col]       = (_Float16)ne;
                s_x[row][128 + col] = (_Float16)sp;
            }
        }
    }
    __syncthreads();   // BARRIER 2

    // ================= phase C: fuse GEMM (MFMA f16) + LN partials =================
    const int wid = t >> 6, wl = t & 63;
    const int arow = wl & 15, kg = wl >> 4;
    float v[4][4];
    {
        f32x4 acc[4];
        #pragma unroll
        for (int i = 0; i < 4; ++i) acc[i] = f32x4{0.f, 0.f, 0.f, 0.f};
        #pragma unroll
        for (int ks = 0; ks < 8; ++ks) {
            f16x8 a = *reinterpret_cast<const f16x8*>(&s_x[arow][ks * 32 + kg * 8]);
            #pragma unroll
            for (int i = 0; i < 4; ++i) {
                const int ct = wid * 4 + i;
                f16x8 b = *reinterpret_cast<const f16x8*>(Wf + (((ks * 16 + ct) * 64) + wl) * 8);
                acc[i] = __builtin_amdgcn_mfma_f32_16x16x32_f16(a, b, acc[i], 0, 0, 0);
            }
        }
        float psum[4] = {0.f, 0.f, 0.f, 0.f};
        float psq[4]  = {0.f, 0.f, 0.f, 0.f};
        #pragma unroll
        for (int i = 0; i < 4; ++i) {
            const int col = (wid * 4 + i) * 16 + arow;
            const float bias = fuse_b[col];
            #pragma unroll
            for (int r = 0; r < 4; ++r) {
                float x = fmaxf(acc[i][r] + bias, 0.0f);
                v[i][r] = x;
                psum[r] += x;
                psq[r]  += x * x;
            }
        }
        #pragma unroll
        for (int r = 0; r < 4; ++r) {
            for (int m = 8; m >= 1; m >>= 1) {
                psum[r] += __shfl_xor(psum[r], m, 16);
                psq[r]  += __shfl_xor(psq[r],  m, 16);
            }
        }
        if (arow == 0) {
            #pragma unroll
            for (int r = 0; r < 4; ++r)
                s_part[kg * 4 + r][wid] = make_float2(psum[r], psq[r]);
        }
    }
    __syncthreads();   // BARRIER 3

    // ================= phase D: LN + store =================
    {
        float lwv[4], lbv[4];
        #pragma unroll
        for (int i = 0; i < 4; ++i) {
            const int col = (wid * 4 + i) * 16 + arow;
            lwv[i] = ln_w[col]; lbv[i] = ln_b[col];
        }
        #pragma unroll
        for (int r = 0; r < 4; ++r) {
            const int row = kg * 4 + r;
            float4 pa = *reinterpret_cast<const float4*>(&s_part[row][0]);
            float4 pb = *reinterpret_cast<const float4*>(&s_part[row][2]);
            float sum = pa.x + pa.z + pb.x + pb.z;
            float sq  = pa.y + pa.w + pb.y + pb.w;
            float mean = sum * (1.0f/256.0f);
            float var  = sq * (1.0f/256.0f) - mean * mean;
            float rstd = rsqrtf(var + 1e-5f);
            const long obase = (rowbase + row) * EMBD;
            #pragma unroll
            for (int i = 0; i < 4; ++i) {
                const int col = (wid * 4 + i) * 16 + arow;
                out_x[obase + col] = (v[i][r] - mean) * rstd * lwv[i] + lbv[i];
            }
        }
    }
}

extern "C" void kernel_launch(void* const* d_in, const int* in_sizes, int n_in,
                              void* d_out, int out_size, void* d_ws, size_t ws_size,
                              hipStream_t stream) {
    const float* state     = (const float*)d_in[0];
    const float* token_W   = (const float*)d_in[1];
    const float* token_b   = (const float*)d_in[2];
    const float* query_W   = (const float*)d_in[3];
    const float* query_b   = (const float*)d_in[4];
    const float* rbs       = (const float*)d_in[5];
    const float* vbias     = (const float*)d_in[6];
    const float* ivbias    = (const float*)d_in[7];
    const float* att_ln_w  = (const float*)d_in[8];
    const float* att_ln_b  = (const float*)d_in[9];
    const float* non_W     = (const float*)d_in[10];
    const float* non_b     = (const float*)d_in[11];
    const float* spfb_W    = (const float*)d_in[12];
    const float* spfb_b    = (const float*)d_in[13];
    const float* sp_gate   = (const float*)d_in[14];
    const float* spatial_W = (const float*)d_in[15];
    const float* spatial_b = (const float*)d_in[16];
    const float* fuse_W    = (const float*)d_in[17];
    const float* fuse_b    = (const float*)d_in[18];
    const float* ln_w      = (const float*)d_in[19];
    const float* ln_b      = (const float*)d_in[20];

    float* out_x  = (float*)d_out;
    float* out_tf = out_x + (size_t)BH * EMBD;

    unsigned short* wsu = (unsigned short*)d_ws;
    const unsigned short* Wf = wsu;                  // 65536 f16
    const unsigned short* Wn = wsu + 65536;          // 4096 f16
    const unsigned short* Ws = wsu + 65536 + 4096;   // 4096 f16
    const unsigned int* qWh = (const unsigned int*)(wsu + 73728);   // 512 uints
    const unsigned int* TWb = qWh + 512;                            // 128 uints

    hipLaunchKernelGGL(prep_w_kernel, dim3(39), dim3(256), 0, stream,
                       fuse_W, non_W, spatial_W, query_W, token_W, token_b, wsu);

    hipLaunchKernelGGL(att_state_enc_kernel, dim3(NBLOCKS), dim3(NTHREADS), 0, stream,
        state, token_W, token_b, query_b, rbs, vbias, ivbias,
        att_ln_w, att_ln_b, non_b, spfb_W, spfb_b, sp_gate, spatial_b,
        Wf, Wn, Ws, qWh, TWb, fuse_b, ln_w, ln_b, out_x, out_tf);
}